// Round 16
// baseline (1904.069 us; speedup 1.0000x reference)
//
#include <hip/hip_runtime.h>
#include <cmath>

#define S_LEN 4096
#define DMODEL 768
#define NHEAD 12
#define DHEAD 64
#define FFDIM 3072
#define NLAYER 12
#define WINR 256

typedef float f32x4 __attribute__((ext_vector_type(4)));
typedef short s4v __attribute__((ext_vector_type(4)));
typedef short s8v __attribute__((ext_vector_type(8)));
typedef __bf16 b8v __attribute__((ext_vector_type(8)));

__device__ __forceinline__ short f2b(float f) {
  unsigned u = __builtin_bit_cast(unsigned, f);
  unsigned r = (u + 0x7fffu + ((u >> 16) & 1u)) >> 16;
  return (short)r;
}
__device__ __forceinline__ float b2f(short s) {
  unsigned u = ((unsigned)(unsigned short)s) << 16;
  return __builtin_bit_cast(float, u);
}
__device__ __forceinline__ f32x4 mfma16(s8v a, s8v b, f32x4 c) {
  return __builtin_amdgcn_mfma_f32_16x16x32_bf16(
      __builtin_bit_cast(b8v, a), __builtin_bit_cast(b8v, b), c, 0, 0, 0);
}
__device__ __forceinline__ void gl_lds16(const short* g, short* l) {
  __builtin_amdgcn_global_load_lds(
      (const __attribute__((address_space(1))) unsigned int*)g,
      (__attribute__((address_space(3))) unsigned int*)l, 16, 0, 0);
}

// log2(e)/8 : folds the 1/sqrt(DH) scale AND the exp->exp2 conversion into Q
#define QSCALE 0.18033688011112042f
#define THR2 11.5415603f  // 8 * log2(e)

// ---------------------------------------------------------------------------
// Weight transpose (64x64 tile body): src [K][N] f32 -> dst [N][K] bf16.
// ---------------------------------------------------------------------------
__device__ __forceinline__ void wtr_tile(const float* __restrict__ src,
                                         short* __restrict__ dst, int K, int N,
                                         int k0, int n0, int t,
                                         short (*tile)[65]) {
  {
    int kr = t >> 2, nc = (t & 3) * 16;
    const float* p = src + (long)(k0 + kr) * N + n0 + nc;
#pragma unroll
    for (int q = 0; q < 4; ++q) {
      float4 f = *(const float4*)(p + q * 4);
      tile[kr][nc + q * 4 + 0] = f2b(f.x);
      tile[kr][nc + q * 4 + 1] = f2b(f.y);
      tile[kr][nc + q * 4 + 2] = f2b(f.z);
      tile[kr][nc + q * 4 + 3] = f2b(f.w);
    }
  }
  __syncthreads();
  {
    int nr = t >> 2, cc = (t & 3) * 16;
    short* q = dst + (long)(n0 + nr) * K + k0 + cc;
    s8v v0, v1;
#pragma unroll
    for (int j = 0; j < 8; ++j) v0[j] = tile[cc + j][nr];
#pragma unroll
    for (int j = 0; j < 8; ++j) v1[j] = tile[cc + 8 + j][nr];
    *(s8v*)q = v0;
    *(s8v*)(q + 8) = v1;
  }
}

__global__ __launch_bounds__(256) void wtr_kernel(const float* __restrict__ src,
                                                  short* __restrict__ dst,
                                                  int K, int N) {
  __shared__ short tile[64][65];
  wtr_tile(src, dst, K, N, blockIdx.y * 64, blockIdx.x * 64, threadIdx.x, tile);
}

__global__ __launch_bounds__(256) void wtr_layer_kernel(
    const float* __restrict__ qkv, const float* __restrict__ ao,
    const float* __restrict__ w1, const float* __restrict__ w2,
    short* __restrict__ lwq, short* __restrict__ lwa, short* __restrict__ lw1,
    short* __restrict__ lw2) {
  __shared__ short tile[64][65];
  const long DD = (long)DMODEL * DMODEL;
  int id = blockIdx.x;
  const float* src;
  short* dst;
  int K, N, nT, kT;
  if (id < 432) {
    int m = id / 144, r = id % 144;
    src = qkv + m * DD; dst = lwq + m * DD;
    K = DMODEL; N = DMODEL; nT = r % 12; kT = r / 12;
  } else if (id < 576) {
    int r = id - 432;
    src = ao; dst = lwa;
    K = DMODEL; N = DMODEL; nT = r % 12; kT = r / 12;
  } else if (id < 1152) {
    int r = id - 576;
    src = w1; dst = lw1;
    K = DMODEL; N = FFDIM; nT = r % 48; kT = r / 48;
  } else {
    int r = id - 1152;
    src = w2; dst = lw2;
    K = FFDIM; N = DMODEL; nT = r % 12; kT = r / 12;
  }
  wtr_tile(src, dst, K, N, kT * 64, nT * 64, threadIdx.x, tile);
}

// ---------------------------------------------------------------------------
// bf16 GEMM, 3-buffer single-barrier pipeline (BK=32, 48KB LDS -> 3 blk/CU):
// per K-step: vmcnt(4) -> s_barrier -> STAGE(k+2) -> ds_read(k) -> MFMA.
// RAW: own stage_k drained pre-barrier (newest allowed = stage_{k+1});
// WAR: buf[(k+2)%3] last read at iter k-1, strictly pre-barrier(k).
// Chunk-XOR swizzled LDS; T5 setprio around the MFMA cluster.
// EPI: 0 none, 1 exact GELU, 2 scale (z==0) by QSCALE.
// OUT: 0 f32+bias, 1 bf16+bias, 2 bf16 partial no-bias (split-K: Koff=z*Klen),
//      3 bf16+bias with bz==2 tile written TRANSPOSED ([n][4096], V^T).
// grid=(N/128, 32, Z), block=256 (4 waves). Requires gridDim.y==32, nwg%8==0.
// ---------------------------------------------------------------------------
template <int EPI, int OUT>
__global__ __launch_bounds__(256, 3) void bgemm_kernel(
    const short* __restrict__ A, const short* __restrict__ Bt,
    const float* __restrict__ bias, void* __restrict__ Cv,
    int N, int K, int Klen, long sB, long sBias, long sC) {
  __shared__ short smem[24576];  // A: 3x4096 | B: 3x4096 (48KB); epi: T tile
  const int t = threadIdx.x, lane = t & 63, w = t >> 6;
  const int lo = lane & 15, hi = lane >> 4;
  const int wm = (w >> 1) * 64, wn = (w & 1) * 64;

  // bijective XCD swizzle: y-chunks of 4 per XCD (gy==32)
  const int gx = gridDim.x;
  const int bid = blockIdx.x + gx * (blockIdx.y + 32 * blockIdx.z);
  const int xcd = bid & 7;
  const int jj_ = bid >> 3;
  const int bx = jj_ % gx;
  const int t2 = jj_ / gx;
  const int by = xcd * 4 + (t2 & 3);
  const int bz = t2 >> 2;

  const long bm = (long)by * 128;
  const int bn = bx * 128;
  Bt += (long)bz * sB;
  const long Koff = (OUT == 2) ? (long)bz * Klen : 0;

  f32x4 acc[4][4];
#pragma unroll
  for (int i = 0; i < 4; ++i)
#pragma unroll
    for (int j = 0; j < 4; ++j) {
      f32x4 zz = {0.f, 0.f, 0.f, 0.f};
      acc[i][j] = zz;
    }

  const int srow = lane >> 2;
  const int schunk = (lane & 3) ^ ((lane >> 3) & 3);
  const short* ga = A + (bm + srow) * (long)K + Koff + schunk * 8;
  const short* gb = Bt + ((long)bn + srow) * K + Koff + schunk * 8;

  // 4 gl_lds per wave per STAGE; As(buf)=smem+buf*4096, Bs=smem+12288+buf*4096
#define STAGE(buf, koff)                                                     \
  {                                                                          \
    _Pragma("unroll") for (int i = 0; i < 2; ++i) {                          \
      const int r0 = i * 64 + w * 16;                                        \
      gl_lds16(ga + (long)r0 * K + (koff), smem + (buf)*4096 + r0 * 32);     \
      gl_lds16(gb + (long)r0 * K + (koff),                                   \
               smem + 12288 + (buf)*4096 + r0 * 32);                         \
    }                                                                        \
  }

  const int nt = Klen >> 5;
  STAGE(0, 0);
  if (nt > 1) STAGE(1, 32);

  const int rchunk = (hi ^ ((lo >> 1) & 3)) * 8;
  int cur = 0;
  for (int kt = 0; kt < nt; ++kt) {
    if (kt + 1 < nt) {
      // own stage_kt drained (newest allowed = stage_{kt+1}); then publish
      asm volatile("s_waitcnt vmcnt(4)\n\ts_barrier" ::: "memory");
    } else {
      asm volatile("s_waitcnt vmcnt(0)\n\ts_barrier" ::: "memory");
    }
    if (kt + 2 < nt) {
      int stg = cur + 2;
      if (stg >= 3) stg -= 3;
      STAGE(stg, (kt + 2) * 32);
    }
    s8v af[4], bf[4];
#pragma unroll
    for (int mi = 0; mi < 4; ++mi)
      af[mi] = *(const s8v*)(smem + cur * 4096 + (wm + mi * 16 + lo) * 32 +
                             rchunk);
#pragma unroll
    for (int ni = 0; ni < 4; ++ni)
      bf[ni] = *(const s8v*)(smem + 12288 + cur * 4096 +
                             (wn + ni * 16 + lo) * 32 + rchunk);
    __builtin_amdgcn_s_setprio(1);
#pragma unroll
    for (int mi = 0; mi < 4; ++mi)
#pragma unroll
      for (int ni = 0; ni < 4; ++ni)
        acc[mi][ni] = mfma16(af[mi], bf[ni], acc[mi][ni]);
    __builtin_amdgcn_s_setprio(0);
    cur = (cur == 2) ? 0 : cur + 1;
  }
#undef STAGE

  const float sc = (EPI == 2 && bz == 0) ? QSCALE : 1.0f;
  float* Cf = (float*)Cv + (long)bz * sC;
  short* Cs = (short*)Cv + (long)bz * sC;
  const float* bp = bias + (long)bz * sBias;

  if (OUT == 3 && bz == 2) {
    // in-LDS transpose of the 128x128 V tile -> write [n][s] layout
    __syncthreads();  // staging buffers must be dead before reuse as T
    short* T = smem;  // needs 16384 shorts
#pragma unroll
    for (int mi = 0; mi < 4; ++mi)
#pragma unroll
      for (int ni = 0; ni < 4; ++ni) {
        const int cl = wn + ni * 16 + lo;
        const float bb = bp[bn + cl];
        const int rb = wm + mi * 16 + hi * 4;
        const int rs = rb ^ ((cl & 15) << 3);  // row-XOR: spread banks
        s4v v;
#pragma unroll
        for (int jj = 0; jj < 4; ++jj) v[jj] = f2b(acc[mi][ni][jj] + bb);
        *(s4v*)&T[cl * 128 + rs] = v;
      }
    __syncthreads();
#pragma unroll
    for (int it = 0; it < 8; ++it) {
      const int id = t + it * 256;
      const int col = id >> 4;        // local n (0..127)
      const int r8 = (id & 15) * 8;   // local s chunk base
      s8v vv = *(const s8v*)&T[col * 128 + (r8 ^ ((col & 15) << 3))];
      *(s8v*)(Cs + (long)(bn + col) * S_LEN + bm + r8) = vv;
    }
    return;
  }

#pragma unroll
  for (int mi = 0; mi < 4; ++mi)
#pragma unroll
    for (int ni = 0; ni < 4; ++ni) {
      int col = bn + wn + ni * 16 + lo;
      float bb = (OUT == 2) ? 0.f : bp[col];
#pragma unroll
      for (int jj = 0; jj < 4; ++jj) {
        long row = bm + wm + mi * 16 + hi * 4 + jj;
        float v = acc[mi][ni][jj] + bb;
        if (EPI == 2) v *= sc;
        if (EPI == 1) v = 0.5f * v * (1.0f + erff(v * 0.7071067811865476f));
        if (OUT == 0)
          Cf[row * N + col] = v;
        else
          Cs[row * N + col] = f2b(v);
      }
    }
}

// ---------------------------------------------------------------------------
// Banded flash attention v8: mask pre-staged in LDS; counted-vmcnt dbuf
// pipeline (T4); K and V^T staged via gl_lds (V^T produced by the QKV GEMM);
// T5 setprio around QK^T and PV MFMA clusters. grid=(64, 12), block=256.
// ---------------------------------------------------------------------------
__global__ __launch_bounds__(256) void attn_kernel(
    const short* __restrict__ Qb, const short* __restrict__ Kb,
    const short* __restrict__ VTg, const int* __restrict__ maskp,
    short* __restrict__ Ob) {
  __shared__ short Ks[2][64 * 64];  // [key][d], swizzled
  __shared__ short VT[2][64 * 64];  // [d][key], swizzled
  __shared__ short Pl[4][16 * 64];  // per-wave [q][key], swizzled
  __shared__ int mask_lds[576];

  const int t = threadIdx.x, lane = t & 63, w = t >> 6;
  const int lo = lane & 15, hi = lane >> 4;

  // XCD swizzle: 8 consecutive q-blocks per XCD
  const int bid = blockIdx.x + 64 * blockIdx.y;
  const int xcd = bid & 7, jb = bid >> 3;
  const int qb = xcd * 8 + (jb & 7), h = jb >> 3;

  const int q0 = qb * 64;
  const int qw = q0 + w * 16;
  short* Plw = Pl[w];

  s8v aq[2];
#pragma unroll
  for (int kg = 0; kg < 2; ++kg)
    aq[kg] = *(const s8v*)(Qb + (long)(qw + lo) * DMODEL + h * 64 + kg * 32 +
                           hi * 8);

  f32x4 o[4];
#pragma unroll
  for (int i = 0; i < 4; ++i) {
    f32x4 zz = {0.f, 0.f, 0.f, 0.f};
    o[i] = zz;
  }
  float rm[4], rl[4];
#pragma unroll
  for (int r = 0; r < 4; ++r) { rm[r] = -1e30f; rl[r] = 0.f; }

  const int kstart = max(0, q0 - WINR);
  const int kend = min(S_LEN, q0 + 64 + WINR);
  const int nt = (kend - kstart) >> 6;

  for (int i = t; i < kend - kstart; i += 256) mask_lds[i] = maskp[kstart + i];
  __syncthreads();

  const int krow = lane >> 3;
  const int kxor = ((lane & 7) ^ krow) * 8;
  const long vrow = (long)(h * 64 + w * 16 + krow) * S_LEN;

#define STAGE_KV(buf, kt)                                                    \
  {                                                                          \
    _Pragma("unroll") for (int i = 0; i < 2; ++i) {                          \
      const int r0 = w * 16 + i * 8;                                         \
      gl_lds16(Kb + (long)((kt) + r0 + krow) * DMODEL + h * 64 + kxor,       \
               Ks[buf] + r0 * 64);                                           \
      gl_lds16(VTg + vrow + (long)i * 8 * S_LEN + (kt) + kxor,               \
               VT[buf] + r0 * 64);                                           \
    }                                                                        \
  }

  STAGE_KV(0, kstart);

  for (int ti = 0; ti < nt; ++ti) {
    const int kt = kstart + ti * 64;
    const int cur = ti & 1;
    if (ti + 1 < nt) {
      STAGE_KV(cur ^ 1, kt + 64);
      asm volatile("s_waitcnt vmcnt(4)\n\ts_barrier" ::: "memory");
    } else {
      asm volatile("s_waitcnt vmcnt(0)\n\ts_barrier" ::: "memory");
    }

    const bool active = (kt + 63 >= qw - WINR) && (kt <= qw + 15 + WINR);
    if (active) {
      f32x4 sacc[4];
#pragma unroll
      for (int i = 0; i < 4; ++i) {
        f32x4 zz = {0.f, 0.f, 0.f, 0.f};
        sacc[i] = zz;
      }
      __builtin_amdgcn_s_setprio(1);
#pragma unroll
      for (int ni = 0; ni < 4; ++ni)
#pragma unroll
        for (int kg = 0; kg < 2; ++kg) {
          const int chunk = (kg * 4 + hi) ^ (lo & 7);
          s8v bk = *(const s8v*)(Ks[cur] + (ni * 16 + lo) * 64 + chunk * 8);
          sacc[ni] = mfma16(aq[kg], bk, sacc[ni]);
        }
      __builtin_amdgcn_s_setprio(0);

      int mval[4];
#pragma unroll
      for (int ni = 0; ni < 4; ++ni)
        mval[ni] = mask_lds[kt - kstart + ni * 16 + lo];

      const bool fullband = (kt >= qw + 15 - WINR) && (kt + 63 <= qw + WINR);

      float m0[4];
      if (fullband) {
#pragma unroll
        for (int jj = 0; jj < 4; ++jj) {
          float mm = -1e30f;
#pragma unroll
          for (int ni = 0; ni < 4; ++ni) {
            float sv = (mval[ni] != 0) ? sacc[ni][jj] : -1e30f;
            sacc[ni][jj] = sv;
            mm = fmaxf(mm, sv);
          }
          mm = fmaxf(mm, __shfl_xor(mm, 1));
          mm = fmaxf(mm, __shfl_xor(mm, 2));
          mm = fmaxf(mm, __shfl_xor(mm, 4));
          mm = fmaxf(mm, __shfl_xor(mm, 8));
          m0[jj] = mm;
        }
      } else {
#pragma unroll
        for (int jj = 0; jj < 4; ++jj) {
          const int qg = qw + hi * 4 + jj;
          float mm = -1e30f;
#pragma unroll
          for (int ni = 0; ni < 4; ++ni) {
            int kg = kt + ni * 16 + lo;
            bool val = (kg >= qg - WINR) && (kg <= qg + WINR) && (mval[ni] != 0);
            float sv = val ? sacc[ni][jj] : -1e30f;
            sacc[ni][jj] = sv;
            mm = fmaxf(mm, sv);
          }
          mm = fmaxf(mm, __shfl_xor(mm, 1));
          mm = fmaxf(mm, __shfl_xor(mm, 2));
          mm = fmaxf(mm, __shfl_xor(mm, 4));
          mm = fmaxf(mm, __shfl_xor(mm, 8));
          m0[jj] = mm;
        }
      }

      bool skipf = true;
#pragma unroll
      for (int jj = 0; jj < 4; ++jj) skipf = skipf && (m0[jj] - rm[jj] <= THR2);

      if (__all(skipf)) {
#pragma unroll
        for (int jj = 0; jj < 4; ++jj) {
          float ts = 0.f;
#pragma unroll
          for (int ni = 0; ni < 4; ++ni) {
            float sv = sacc[ni][jj];
            float p = (sv > -1e29f) ? exp2f(sv - rm[jj]) : 0.f;
            sacc[ni][jj] = p;
            ts += p;
          }
          ts += __shfl_xor(ts, 1);
          ts += __shfl_xor(ts, 2);
          ts += __shfl_xor(ts, 4);
          ts += __shfl_xor(ts, 8);
          rl[jj] += ts;
        }
      } else {
#pragma unroll
        for (int jj = 0; jj < 4; ++jj) {
          float mnew = fmaxf(rm[jj], m0[jj]);
          float scl = exp2f(rm[jj] - mnew);
          rm[jj] = mnew;
          float ts = 0.f;
#pragma unroll
          for (int ni = 0; ni < 4; ++ni) {
            float sv = sacc[ni][jj];
            float p = (sv > -1e29f) ? exp2f(sv - mnew) : 0.f;
            sacc[ni][jj] = p;
            ts += p;
          }
          ts += __shfl_xor(ts, 1);
          ts += __shfl_xor(ts, 2);
          ts += __shfl_xor(ts, 4);
          ts += __shfl_xor(ts, 8);
          rl[jj] = rl[jj] * scl + ts;
#pragma unroll
          for (int di = 0; di < 4; ++di) o[di][jj] *= scl;
        }
      }

#pragma unroll
      for (int jj = 0; jj < 4; ++jj) {
        const int qr = hi * 4 + jj;
#pragma unroll
        for (int ni = 0; ni < 4; ++ni) {
          const int chunk = (ni * 2 + (lo >> 3)) ^ (qr & 7);
          Plw[qr * 64 + chunk * 8 + (lo & 7)] = f2b(sacc[ni][jj]);
        }
      }

      s8v ap[2];
#pragma unroll
      for (int kg = 0; kg < 2; ++kg) {
        const int chunk = (kg * 4 + hi) ^ (lo & 7);
        ap[kg] = *(const s8v*)(Plw + lo * 64 + chunk * 8);
      }
      __builtin_amdgcn_s_setprio(1);
#pragma unroll
      for (int di = 0; di < 4; ++di)
#pragma unroll
        for (int kg = 0; kg < 2; ++kg) {
          const int chunk = (kg * 4 + hi) ^ (lo & 7);
          s8v bv = *(const s8v*)(VT[cur] + (di * 16 + lo) * 64 + chunk * 8);
          o[di] = mfma16(ap[kg], bv, o[di]);
        }
      __builtin_amdgcn_s_setprio(0);
    }
    asm volatile("s_barrier" ::: "memory");
  }
#undef STAGE_KV

#pragma unroll
  for (int di = 0; di < 4; ++di)
#pragma unroll
    for (int jj = 0; jj < 4; ++jj) {
      long row = qw + hi * 4 + jj;
      Ob[row * DMODEL + h * 64 + di * 16 + lo] = f2b(o[di][jj] / rl[jj]);
    }
}

// ---------------------------------------------------------------------------
// Embedding + LayerNorm -> bf16 Xb. grid=4096, block=256.
// ---------------------------------------------------------------------------
__global__ __launch_bounds__(256) void embed_ln_kernel(
    const int* __restrict__ tok, const float* __restrict__ wemb,
    const float* __restrict__ pemb, const float* __restrict__ gs,
    const float* __restrict__ gb, short* __restrict__ Xb) {
  __shared__ float sm1[4], sm2[4];
  const int row = blockIdx.x;
  const int tk = tok[row];
  float v[3];
  float s = 0.f, q = 0.f;
#pragma unroll
  for (int i = 0; i < 3; ++i) {
    int c = threadIdx.x + i * 256;
    float x = wemb[(long)tk * DMODEL + c] + pemb[(long)(row + 2) * DMODEL + c];
    v[i] = x;
    s += x;
    q += x * x;
  }
#pragma unroll
  for (int off = 32; off; off >>= 1) {
    s += __shfl_down(s, off);
    q += __shfl_down(q, off);
  }
  int w = threadIdx.x >> 6;
  if ((threadIdx.x & 63) == 0) { sm1[w] = s; sm2[w] = q; }
  __syncthreads();
  s = sm1[0] + sm1[1] + sm1[2] + sm1[3];
  q = sm2[0] + sm2[1] + sm2[2] + sm2[3];
  float mu = s * (1.f / DMODEL);
  float var = q * (1.f / DMODEL) - mu * mu;
  float inv = rsqrtf(var + 1e-5f);
#pragma unroll
  for (int i = 0; i < 3; ++i) {
    int c = threadIdx.x + i * 256;
    float y = (v[i] - mu) * inv * gs[c] + gb[c];
    Xb[(long)row * DMODEL + c] = f2b(y);
  }
}

// ---------------------------------------------------------------------------
// Xb = LayerNorm(Xb + P0b + P1b + bias) — bf16 residual, vectorized (G13):
// 192 threads x 4 contiguous bf16 (8B/lane loads). grid=4096.
// ---------------------------------------------------------------------------
__global__ __launch_bounds__(192) void resln2_kernel(
    short* __restrict__ Xb, const short* __restrict__ P0b,
    const short* __restrict__ P1b, const float* __restrict__ bias,
    const float* __restrict__ gs, const float* __restrict__ gb) {
  __shared__ float sm1[3], sm2[3];
  const int row = blockIdx.x;
  const int t = threadIdx.x;
  const int c = t * 4;
  const long ix = (long)row * DMODEL + c;
  s4v xv = *(const s4v*)&Xb[ix];
  s4v p0 = *(const s4v*)&P0b[ix];
  s4v p1 = *(const s4v*)&P1b[ix];
  float4 bb = *(const float4*)&bias[c];
  float v[4];
  v[0] = b2f(xv[0]) + b2f(p0[0]) + b2f(p1[0]) + bb.x;
  v[1] = b2f(xv[1]) + b2f(p0[1]) + b2f(p1[1]) + bb.y;
  v[2] = b2f(xv[2]) + b2f(p0[2]) + b2f(p1[2]) + bb.z;
  v[3] = b2f(xv[3]) + b2f(p0[3]) + b2f(p1[3]) + bb.w;
  float s = v[0] + v[1] + v[2] + v[3];
  float q = v[0] * v[0] + v[1] * v[1] + v[2] * v[2] + v[3] * v[3];
#pragma unroll
  for (int off = 32; off; off >>= 1) {
    s += __shfl_down(s, off);
    q += __shfl_down(q, off);
  }
  const int w = t >> 6;
  if ((t & 63) == 0) { sm1[w] = s; sm2[w] = q; }
  __syncthreads();
  s = sm1[0] + sm1[1] + sm1[2];
  q = sm2[0] + sm2[1] + sm2[2];
  float mu = s * (1.f / DMODEL);
  float var = q * (1.f / DMODEL) - mu * mu;
  float inv = rsqrtf(var + 1e-5f);
  float4 gsv = *(const float4*)&gs[c];
  float4 gbv = *(const float4*)&gb[c];
  s4v y;
  y[0] = f2b((v[0] - mu) * inv * gsv.x + gbv.x);
  y[1] = f2b((v[1] - mu) * inv * gsv.y + gbv.y);
  y[2] = f2b((v[2] - mu) * inv * gsv.z + gbv.z);
  y[3] = f2b((v[3] - mu) * inv * gsv.w + gbv.w);
  *(s4v*)&Xb[ix] = y;
}

// ---------------------------------------------------------------------------
// out[row] = dot(H3[row,:512] (bf16), w4[:,0] (f32)) + b4[0].
// ---------------------------------------------------------------------------
__global__ __launch_bounds__(256) void cls_final_kernel(
    const short* __restrict__ Hh, const float* __restrict__ w4,
    const float* __restrict__ b4, float* __restrict__ out) {
  const int w = threadIdx.x >> 6, lane = threadIdx.x & 63;
  const int row = blockIdx.x * 4 + w;
  float s = 0.f;
#pragma unroll
  for (int j = 0; j < 8; ++j) {
    int k = lane + j * 64;
    s += b2f(Hh[(long)row * 512 + k]) * w4[k * 2];
  }
#pragma unroll
  for (int off = 32; off; off >>= 1) s += __shfl_down(s, off);
  if (lane == 0) out[row] = s + b4[0];
}

// ---------------------------------------------------------------------------
extern "C" void kernel_launch(void* const* d_in, const int* in_sizes, int n_in,
                              void* d_out, int out_size, void* d_ws,
                              size_t ws_size, hipStream_t stream) {
  const int* essay = (const int*)d_in[0];
  const float* wemb = (const float*)d_in[1];
  const float* pemb = (const float*)d_in[2];
  const float* eln_s = (const float*)d_in[3];
  const float* eln_b = (const float*)d_in[4];
  const float* qkv_w = (const float*)d_in[5];
  const float* qkv_b = (const float*)d_in[6];
  const float* aow = (const float*)d_in[7];
  const float* aob = (const float*)d_in[8];
  const float* aln_s = (const float*)d_in[9];
  const float* aln_b = (const float*)d_in[10];
  const float* w1 = (const float*)d_in[11];
  const float* b1 = (const float*)d_in[12];
  const float* w2 = (const float*)d_in[13];
  const float* b2 = (const float*)d_in[14];
  const float* fln_s = (const float*)d_in[15];
  const float* fln_b = (const float*)d_in[16];
  const float* c1w = (const float*)d_in[17];
  const float* c1b = (const float*)d_in[18];
  const float* c2w = (const float*)d_in[19];
  const float* c2b = (const float*)d_in[20];
  const float* c3w = (const float*)d_in[21];
  const float* c3b = (const float*)d_in[22];
  const float* c4w = (const float*)d_in[23];
  const float* c4b = (const float*)d_in[24];

  const long SD = (long)S_LEN * DMODEL;
  const long SF = (long)S_LEN * FFDIM;
  const long SH = (long)S_LEN * 512;
  const long DD = (long)DMODEL * DMODEL;
  const long DF = (long)DMODEL * FFDIM;

  short* P0b = (short*)d_ws;
  short* P1b = P0b + SD;
  short* lwq = P1b + SD;
  short* lwa = lwq + 3 * DD;
  short* lw1 = lwa + DD;
  short* lw2 = lw1 + DF;
  short* c1T = lw2 + DF;
  short* c2T = c1T + (long)DMODEL * 512;
  short* c3T = c2T + 512L * 512;
  short* Xb = c3T + 512L * 512;
  short* QKVb = Xb + SD;   // Q | K row-major; V slice holds V^T [768][4096]
  short* T1b = QKVb + 3 * SD;
  short* T2b = T1b + SD;
  short* H1 = T2b + SF;
  short* H2 = H1 + SH;
  short* H3 = H2 + SH;
  const long needed = (char*)(H3 + SH) - (char*)d_ws;
  if (ws_size < (size_t)needed) return;

  const int* maskp = essay + S_LEN;

  embed_ln_kernel<<<S_LEN, 256, 0, stream>>>(essay, wemb, pemb, eln_s, eln_b,
                                             Xb);

  for (int l = 0; l < NLAYER; ++l) {
    wtr_layer_kernel<<<1728, 256, 0, stream>>>(
        qkv_w + l * 3 * DD, aow + l * DD, w1 + l * DF, w2 + l * DF, lwq, lwa,
        lw1, lw2);

    // QKV: z==0 Q (scaled), z==1 K, z==2 V written transposed in-epilogue
    bgemm_kernel<2, 3><<<dim3(6, 32, 3), 256, 0, stream>>>(
        Xb, lwq, qkv_b + (long)l * 3 * DMODEL, QKVb, DMODEL, DMODEL, DMODEL, DD,
        DMODEL, SD);
    attn_kernel<<<dim3(64, 12), 256, 0, stream>>>(QKVb, QKVb + SD,
                                                  QKVb + 2 * SD, maskp, T1b);
    // attn-out projection: split-K x2 -> bf16 partials P0b,P1b
    bgemm_kernel<0, 2><<<dim3(6, 32, 2), 256, 0, stream>>>(
        T1b, lwa, aob, P0b, DMODEL, DMODEL, 384, 0, 0, SD);
    resln2_kernel<<<S_LEN, 192, 0, stream>>>(Xb, P0b, P1b,
                                             aob + (long)l * DMODEL,
                                             aln_s + (long)l * DMODEL,
                                             aln_b + (long)l * DMODEL);
    // FFN1 (128x128 kernel, GELU epilogue)
    bgemm_kernel<1, 1><<<dim3(24, 32, 1), 256, 0, stream>>>(
        Xb, lw1, b1 + (long)l * FFDIM, T2b, FFDIM, DMODEL, DMODEL, 0, 0, 0);
    // FFN down-projection: split-K x2 -> bf16 partials P0b,P1b
    bgemm_kernel<0, 2><<<dim3(6, 32, 2), 256, 0, stream>>>(
        T2b, lw2, b2, P0b, DMODEL, FFDIM, 1536, 0, 0, SD);
    resln2_kernel<<<S_LEN, 192, 0, stream>>>(Xb, P0b, P1b,
                                             b2 + (long)l * DMODEL,
                                             fln_s + (long)l * DMODEL,
                                             fln_b + (long)l * DMODEL);
  }

  wtr_kernel<<<dim3(8, 12), 256, 0, stream>>>(c1w, c1T, DMODEL, 512);
  wtr_kernel<<<dim3(8, 8), 256, 0, stream>>>(c2w, c2T, 512, 512);
  wtr_kernel<<<dim3(8, 8), 256, 0, stream>>>(c3w, c3T, 512, 512);

  bgemm_kernel<0, 1><<<dim3(4, 32, 1), 256, 0, stream>>>(
      Xb, c1T, c1b, H1, 512, DMODEL, DMODEL, 0, 0, 0);
  bgemm_kernel<0, 1><<<dim3(4, 32, 1), 256, 0, stream>>>(H1, c2T, c2b, H2, 512,
                                                         512, 512, 0, 0, 0);
  bgemm_kernel<0, 1><<<dim3(4, 32, 1), 256, 0, stream>>>(H2, c3T, c3b, H3, 512,
                                                         512, 512, 0, 0, 0);
  cls_final_kernel<<<S_LEN / 4, 256, 0, stream>>>(H3, c4w, c4b, (float*)d_out);
}

// Round 17
// 1900.208 us; speedup vs baseline: 1.0020x; 1.0020x over previous
//
#include <hip/hip_runtime.h>
#include <cmath>

#define S_LEN 4096
#define DMODEL 768
#define NHEAD 12
#define DHEAD 64
#define FFDIM 3072
#define NLAYER 12
#define WINR 256

typedef float f32x4 __attribute__((ext_vector_type(4)));
typedef short s4v __attribute__((ext_vector_type(4)));
typedef short s8v __attribute__((ext_vector_type(8)));
typedef __bf16 b8v __attribute__((ext_vector_type(8)));

__device__ __forceinline__ short f2b(float f) {
  unsigned u = __builtin_bit_cast(unsigned, f);
  unsigned r = (u + 0x7fffu + ((u >> 16) & 1u)) >> 16;
  return (short)r;
}
__device__ __forceinline__ float b2f(short s) {
  unsigned u = ((unsigned)(unsigned short)s) << 16;
  return __builtin_bit_cast(float, u);
}
__device__ __forceinline__ f32x4 mfma16(s8v a, s8v b, f32x4 c) {
  return __builtin_amdgcn_mfma_f32_16x16x32_bf16(
      __builtin_bit_cast(b8v, a), __builtin_bit_cast(b8v, b), c, 0, 0, 0);
}
__device__ __forceinline__ void gl_lds16(const short* g, short* l) {
  __builtin_amdgcn_global_load_lds(
      (const __attribute__((address_space(1))) unsigned int*)g,
      (__attribute__((address_space(3))) unsigned int*)l, 16, 0, 0);
}

// log2(e)/8 : folds the 1/sqrt(DH) scale AND the exp->exp2 conversion into Q
#define QSCALE 0.18033688011112042f
#define THR2 11.5415603f  // 8 * log2(e)

// ---------------------------------------------------------------------------
// Weight transpose (64x64 tile body): src [K][N] f32 -> dst [N][K] bf16.
// ---------------------------------------------------------------------------
__device__ __forceinline__ void wtr_tile(const float* __restrict__ src,
                                         short* __restrict__ dst, int K, int N,
                                         int k0, int n0, int t,
                                         short (*tile)[65]) {
  {
    int kr = t >> 2, nc = (t & 3) * 16;
    const float* p = src + (long)(k0 + kr) * N + n0 + nc;
#pragma unroll
    for (int q = 0; q < 4; ++q) {
      float4 f = *(const float4*)(p + q * 4);
      tile[kr][nc + q * 4 + 0] = f2b(f.x);
      tile[kr][nc + q * 4 + 1] = f2b(f.y);
      tile[kr][nc + q * 4 + 2] = f2b(f.z);
      tile[kr][nc + q * 4 + 3] = f2b(f.w);
    }
  }
  __syncthreads();
  {
    int nr = t >> 2, cc = (t & 3) * 16;
    short* q = dst + (long)(n0 + nr) * K + k0 + cc;
    s8v v0, v1;
#pragma unroll
    for (int j = 0; j < 8; ++j) v0[j] = tile[cc + j][nr];
#pragma unroll
    for (int j = 0; j < 8; ++j) v1[j] = tile[cc + 8 + j][nr];
    *(s8v*)q = v0;
    *(s8v*)(q + 8) = v1;
  }
}

__global__ __launch_bounds__(256) void wtr_kernel(const float* __restrict__ src,
                                                  short* __restrict__ dst,
                                                  int K, int N) {
  __shared__ short tile[64][65];
  wtr_tile(src, dst, K, N, blockIdx.y * 64, blockIdx.x * 64, threadIdx.x, tile);
}

__global__ __launch_bounds__(256) void wtr_layer_kernel(
    const float* __restrict__ qkv, const float* __restrict__ ao,
    const float* __restrict__ w1, const float* __restrict__ w2,
    short* __restrict__ lwq, short* __restrict__ lwa, short* __restrict__ lw1,
    short* __restrict__ lw2) {
  __shared__ short tile[64][65];
  const long DD = (long)DMODEL * DMODEL;
  int id = blockIdx.x;
  const float* src;
  short* dst;
  int K, N, nT, kT;
  if (id < 432) {
    int m = id / 144, r = id % 144;
    src = qkv + m * DD; dst = lwq + m * DD;
    K = DMODEL; N = DMODEL; nT = r % 12; kT = r / 12;
  } else if (id < 576) {
    int r = id - 432;
    src = ao; dst = lwa;
    K = DMODEL; N = DMODEL; nT = r % 12; kT = r / 12;
  } else if (id < 1152) {
    int r = id - 576;
    src = w1; dst = lw1;
    K = DMODEL; N = FFDIM; nT = r % 48; kT = r / 48;
  } else {
    int r = id - 1152;
    src = w2; dst = lw2;
    K = FFDIM; N = DMODEL; nT = r % 12; kT = r / 12;
  }
  wtr_tile(src, dst, K, N, kT * 64, nT * 64, threadIdx.x, tile);
}

// ---------------------------------------------------------------------------
// bf16 GEMM, 2-phase double-buffered, BK=32 (32KB LDS -> 4 blocks/CU),
// counted-vmcnt pipeline (T4). Chunk-XOR swizzled LDS. T5 setprio around
// the MFMA cluster.
// EPI: 0 none, 1 exact GELU, 2 scale (z==0) by QSCALE.
// OUT: 0 f32+bias, 1 bf16+bias, 2 bf16 partial no-bias (split-K: Koff=z*Klen),
//      3 bf16+bias with bz==2 tile written TRANSPOSED ([n][4096], V^T for attn)
//        via in-LDS transpose reusing the staging buffers.
// grid=(N/128, 32, Z), block=256 (4 waves). Requires gridDim.y==32, nwg%8==0.
// ---------------------------------------------------------------------------
template <int EPI, int OUT>
__global__ __launch_bounds__(256, 4) void bgemm_kernel(
    const short* __restrict__ A, const short* __restrict__ Bt,
    const float* __restrict__ bias, void* __restrict__ Cv,
    int N, int K, int Klen, long sB, long sBias, long sC) {
  __shared__ short smem[16384];  // As[2][4096] | Bs[2][4096]; epilogue: T tile
  const int t = threadIdx.x, lane = t & 63, w = t >> 6;
  const int lo = lane & 15, hi = lane >> 4;
  const int wm = (w >> 1) * 64, wn = (w & 1) * 64;

  // bijective XCD swizzle: y-chunks of 4 per XCD (gy==32)
  const int gx = gridDim.x;
  const int bid = blockIdx.x + gx * (blockIdx.y + 32 * blockIdx.z);
  const int xcd = bid & 7;
  const int jj_ = bid >> 3;
  const int bx = jj_ % gx;
  const int t2 = jj_ / gx;
  const int by = xcd * 4 + (t2 & 3);
  const int bz = t2 >> 2;

  const long bm = (long)by * 128;
  const int bn = bx * 128;
  Bt += (long)bz * sB;
  const long Koff = (OUT == 2) ? (long)bz * Klen : 0;

  f32x4 acc[4][4];
#pragma unroll
  for (int i = 0; i < 4; ++i)
#pragma unroll
    for (int j = 0; j < 4; ++j) {
      f32x4 zz = {0.f, 0.f, 0.f, 0.f};
      acc[i][j] = zz;
    }

  const int srow = lane >> 2;
  const int schunk = (lane & 3) ^ ((lane >> 3) & 3);
  const short* ga = A + (bm + srow) * (long)K + Koff + schunk * 8;
  const short* gb = Bt + ((long)bn + srow) * K + Koff + schunk * 8;

  // 4 gl_lds per wave per STAGE; As(buf)=smem+buf*4096, Bs(buf)=smem+8192+...
#define STAGE(buf, koff)                                                     \
  {                                                                          \
    _Pragma("unroll") for (int i = 0; i < 2; ++i) {                          \
      const int r0 = i * 64 + w * 16;                                        \
      gl_lds16(ga + (long)r0 * K + (koff), smem + (buf)*4096 + r0 * 32);     \
      gl_lds16(gb + (long)r0 * K + (koff),                                   \
               smem + 8192 + (buf)*4096 + r0 * 32);                          \
    }                                                                        \
  }

  STAGE(0, 0);

  const int nt = Klen >> 5;
  const int rchunk = (hi ^ ((lo >> 1) & 3)) * 8;
  for (int kt = 0; kt < nt; ++kt) {
    const int cur = kt & 1;
    if (kt + 1 < nt) {
      STAGE(cur ^ 1, (kt + 1) * 32);
      asm volatile("s_waitcnt vmcnt(4)\n\ts_barrier" ::: "memory");
    } else {
      asm volatile("s_waitcnt vmcnt(0)\n\ts_barrier" ::: "memory");
    }
    s8v af[4], bf[4];
#pragma unroll
    for (int mi = 0; mi < 4; ++mi)
      af[mi] = *(const s8v*)(smem + cur * 4096 + (wm + mi * 16 + lo) * 32 +
                             rchunk);
#pragma unroll
    for (int ni = 0; ni < 4; ++ni)
      bf[ni] = *(const s8v*)(smem + 8192 + cur * 4096 +
                             (wn + ni * 16 + lo) * 32 + rchunk);
    __builtin_amdgcn_s_setprio(1);
#pragma unroll
    for (int mi = 0; mi < 4; ++mi)
#pragma unroll
      for (int ni = 0; ni < 4; ++ni)
        acc[mi][ni] = mfma16(af[mi], bf[ni], acc[mi][ni]);
    __builtin_amdgcn_s_setprio(0);
    asm volatile("s_barrier" ::: "memory");
  }
#undef STAGE

  const float sc = (EPI == 2 && bz == 0) ? QSCALE : 1.0f;
  float* Cf = (float*)Cv + (long)bz * sC;
  short* Cs = (short*)Cv + (long)bz * sC;
  const float* bp = bias + (long)bz * sBias;

  if (OUT == 3 && bz == 2) {
    // in-LDS transpose of the 128x128 V tile -> write [n][s] layout
    short* T = smem;  // 16384 shorts
#pragma unroll
    for (int mi = 0; mi < 4; ++mi)
#pragma unroll
      for (int ni = 0; ni < 4; ++ni) {
        const int cl = wn + ni * 16 + lo;
        const float bb = bp[bn + cl];
        const int rb = wm + mi * 16 + hi * 4;
        const int rs = rb ^ ((cl & 15) << 3);  // row-XOR: spread banks
        s4v v;
#pragma unroll
        for (int jj = 0; jj < 4; ++jj) v[jj] = f2b(acc[mi][ni][jj] + bb);
        *(s4v*)&T[cl * 128 + rs] = v;
      }
    __syncthreads();
#pragma unroll
    for (int it = 0; it < 8; ++it) {
      const int id = t + it * 256;
      const int col = id >> 4;        // local n (0..127)
      const int r8 = (id & 15) * 8;   // local s chunk base
      s8v vv = *(const s8v*)&T[col * 128 + (r8 ^ ((col & 15) << 3))];
      *(s8v*)(Cs + (long)(bn + col) * S_LEN + bm + r8) = vv;
    }
    return;
  }

#pragma unroll
  for (int mi = 0; mi < 4; ++mi)
#pragma unroll
    for (int ni = 0; ni < 4; ++ni) {
      int col = bn + wn + ni * 16 + lo;
      float bb = (OUT == 2) ? 0.f : bp[col];
#pragma unroll
      for (int jj = 0; jj < 4; ++jj) {
        long row = bm + wm + mi * 16 + hi * 4 + jj;
        float v = acc[mi][ni][jj] + bb;
        if (EPI == 2) v *= sc;
        if (EPI == 1) v = 0.5f * v * (1.0f + erff(v * 0.7071067811865476f));
        if (OUT == 0)
          Cf[row * N + col] = v;
        else
          Cs[row * N + col] = f2b(v);
      }
    }
}

// ---------------------------------------------------------------------------
// Banded flash attention v8: mask pre-staged in LDS; counted-vmcnt dbuf
// pipeline (T4); K and V^T staged via gl_lds (V^T produced by the QKV GEMM);
// T5 setprio around QK^T and PV MFMA clusters. grid=(64, 12), block=256.
// ---------------------------------------------------------------------------
__global__ __launch_bounds__(256) void attn_kernel(
    const short* __restrict__ Qb, const short* __restrict__ Kb,
    const short* __restrict__ VTg, const int* __restrict__ maskp,
    short* __restrict__ Ob) {
  __shared__ short Ks[2][64 * 64];  // [key][d], swizzled
  __shared__ short VT[2][64 * 64];  // [d][key], swizzled
  __shared__ short Pl[4][16 * 64];  // per-wave [q][key], swizzled
  __shared__ int mask_lds[576];

  const int t = threadIdx.x, lane = t & 63, w = t >> 6;
  const int lo = lane & 15, hi = lane >> 4;

  // XCD swizzle: 8 consecutive q-blocks per XCD
  const int bid = blockIdx.x + 64 * blockIdx.y;
  const int xcd = bid & 7, jb = bid >> 3;
  const int qb = xcd * 8 + (jb & 7), h = jb >> 3;

  const int q0 = qb * 64;
  const int qw = q0 + w * 16;
  short* Plw = Pl[w];

  s8v aq[2];
#pragma unroll
  for (int kg = 0; kg < 2; ++kg)
    aq[kg] = *(const s8v*)(Qb + (long)(qw + lo) * DMODEL + h * 64 + kg * 32 +
                           hi * 8);

  f32x4 o[4];
#pragma unroll
  for (int i = 0; i < 4; ++i) {
    f32x4 zz = {0.f, 0.f, 0.f, 0.f};
    o[i] = zz;
  }
  float rm[4], rl[4];
#pragma unroll
  for (int r = 0; r < 4; ++r) { rm[r] = -1e30f; rl[r] = 0.f; }

  const int kstart = max(0, q0 - WINR);
  const int kend = min(S_LEN, q0 + 64 + WINR);
  const int nt = (kend - kstart) >> 6;

  for (int i = t; i < kend - kstart; i += 256) mask_lds[i] = maskp[kstart + i];
  __syncthreads();

  const int krow = lane >> 3;
  const int kxor = ((lane & 7) ^ krow) * 8;
  const long vrow = (long)(h * 64 + w * 16 + krow) * S_LEN;

#define STAGE_KV(buf, kt)                                                    \
  {                                                                          \
    _Pragma("unroll") for (int i = 0; i < 2; ++i) {                          \
      const int r0 = w * 16 + i * 8;                                         \
      gl_lds16(Kb + (long)((kt) + r0 + krow) * DMODEL + h * 64 + kxor,       \
               Ks[buf] + r0 * 64);                                           \
      gl_lds16(VTg + vrow + (long)i * 8 * S_LEN + (kt) + kxor,               \
               VT[buf] + r0 * 64);                                           \
    }                                                                        \
  }

  STAGE_KV(0, kstart);

  for (int ti = 0; ti < nt; ++ti) {
    const int kt = kstart + ti * 64;
    const int cur = ti & 1;
    if (ti + 1 < nt) {
      STAGE_KV(cur ^ 1, kt + 64);
      asm volatile("s_waitcnt vmcnt(4)\n\ts_barrier" ::: "memory");
    } else {
      asm volatile("s_waitcnt vmcnt(0)\n\ts_barrier" ::: "memory");
    }

    const bool active = (kt + 63 >= qw - WINR) && (kt <= qw + 15 + WINR);
    if (active) {
      f32x4 sacc[4];
#pragma unroll
      for (int i = 0; i < 4; ++i) {
        f32x4 zz = {0.f, 0.f, 0.f, 0.f};
        sacc[i] = zz;
      }
      __builtin_amdgcn_s_setprio(1);
#pragma unroll
      for (int ni = 0; ni < 4; ++ni)
#pragma unroll
        for (int kg = 0; kg < 2; ++kg) {
          const int chunk = (kg * 4 + hi) ^ (lo & 7);
          s8v bk = *(const s8v*)(Ks[cur] + (ni * 16 + lo) * 64 + chunk * 8);
          sacc[ni] = mfma16(aq[kg], bk, sacc[ni]);
        }
      __builtin_amdgcn_s_setprio(0);

      int mval[4];
#pragma unroll
      for (int ni = 0; ni < 4; ++ni)
        mval[ni] = mask_lds[kt - kstart + ni * 16 + lo];

      const bool fullband = (kt >= qw + 15 - WINR) && (kt + 63 <= qw + WINR);

      float m0[4];
      if (fullband) {
#pragma unroll
        for (int jj = 0; jj < 4; ++jj) {
          float mm = -1e30f;
#pragma unroll
          for (int ni = 0; ni < 4; ++ni) {
            float sv = (mval[ni] != 0) ? sacc[ni][jj] : -1e30f;
            sacc[ni][jj] = sv;
            mm = fmaxf(mm, sv);
          }
          mm = fmaxf(mm, __shfl_xor(mm, 1));
          mm = fmaxf(mm, __shfl_xor(mm, 2));
          mm = fmaxf(mm, __shfl_xor(mm, 4));
          mm = fmaxf(mm, __shfl_xor(mm, 8));
          m0[jj] = mm;
        }
      } else {
#pragma unroll
        for (int jj = 0; jj < 4; ++jj) {
          const int qg = qw + hi * 4 + jj;
          float mm = -1e30f;
#pragma unroll
          for (int ni = 0; ni < 4; ++ni) {
            int kg = kt + ni * 16 + lo;
            bool val = (kg >= qg - WINR) && (kg <= qg + WINR) && (mval[ni] != 0);
            float sv = val ? sacc[ni][jj] : -1e30f;
            sacc[ni][jj] = sv;
            mm = fmaxf(mm, sv);
          }
          mm = fmaxf(mm, __shfl_xor(mm, 1));
          mm = fmaxf(mm, __shfl_xor(mm, 2));
          mm = fmaxf(mm, __shfl_xor(mm, 4));
          mm = fmaxf(mm, __shfl_xor(mm, 8));
          m0[jj] = mm;
        }
      }

      bool skipf = true;
#pragma unroll
      for (int jj = 0; jj < 4; ++jj) skipf = skipf && (m0[jj] - rm[jj] <= THR2);

      if (__all(skipf)) {
#pragma unroll
        for (int jj = 0; jj < 4; ++jj) {
          float ts = 0.f;
#pragma unroll
          for (int ni = 0; ni < 4; ++ni) {
            float sv = sacc[ni][jj];
            float p = (sv > -1e29f) ? exp2f(sv - rm[jj]) : 0.f;
            sacc[ni][jj] = p;
            ts += p;
          }
          ts += __shfl_xor(ts, 1);
          ts += __shfl_xor(ts, 2);
          ts += __shfl_xor(ts, 4);
          ts += __shfl_xor(ts, 8);
          rl[jj] += ts;
        }
      } else {
#pragma unroll
        for (int jj = 0; jj < 4; ++jj) {
          float mnew = fmaxf(rm[jj], m0[jj]);
          float scl = exp2f(rm[jj] - mnew);
          rm[jj] = mnew;
          float ts = 0.f;
#pragma unroll
          for (int ni = 0; ni < 4; ++ni) {
            float sv = sacc[ni][jj];
            float p = (sv > -1e29f) ? exp2f(sv - mnew) : 0.f;
            sacc[ni][jj] = p;
            ts += p;
          }
          ts += __shfl_xor(ts, 1);
          ts += __shfl_xor(ts, 2);
          ts += __shfl_xor(ts, 4);
          ts += __shfl_xor(ts, 8);
          rl[jj] = rl[jj] * scl + ts;
#pragma unroll
          for (int di = 0; di < 4; ++di) o[di][jj] *= scl;
        }
      }

#pragma unroll
      for (int jj = 0; jj < 4; ++jj) {
        const int qr = hi * 4 + jj;
#pragma unroll
        for (int ni = 0; ni < 4; ++ni) {
          const int chunk = (ni * 2 + (lo >> 3)) ^ (qr & 7);
          Plw[qr * 64 + chunk * 8 + (lo & 7)] = f2b(sacc[ni][jj]);
        }
      }

      s8v ap[2];
#pragma unroll
      for (int kg = 0; kg < 2; ++kg) {
        const int chunk = (kg * 4 + hi) ^ (lo & 7);
        ap[kg] = *(const s8v*)(Plw + lo * 64 + chunk * 8);
      }
      __builtin_amdgcn_s_setprio(1);
#pragma unroll
      for (int di = 0; di < 4; ++di)
#pragma unroll
        for (int kg = 0; kg < 2; ++kg) {
          const int chunk = (kg * 4 + hi) ^ (lo & 7);
          s8v bv = *(const s8v*)(VT[cur] + (di * 16 + lo) * 64 + chunk * 8);
          o[di] = mfma16(ap[kg], bv, o[di]);
        }
      __builtin_amdgcn_s_setprio(0);
    }
    asm volatile("s_barrier" ::: "memory");
  }
#undef STAGE_KV

#pragma unroll
  for (int di = 0; di < 4; ++di)
#pragma unroll
    for (int jj = 0; jj < 4; ++jj) {
      long row = qw + hi * 4 + jj;
      Ob[row * DMODEL + h * 64 + di * 16 + lo] = f2b(o[di][jj] / rl[jj]);
    }
}

// ---------------------------------------------------------------------------
// Embedding + LayerNorm -> bf16 Xb. grid=4096, block=256.
// ---------------------------------------------------------------------------
__global__ __launch_bounds__(256) void embed_ln_kernel(
    const int* __restrict__ tok, const float* __restrict__ wemb,
    const float* __restrict__ pemb, const float* __restrict__ gs,
    const float* __restrict__ gb, short* __restrict__ Xb) {
  __shared__ float sm1[4], sm2[4];
  const int row = blockIdx.x;
  const int tk = tok[row];
  float v[3];
  float s = 0.f, q = 0.f;
#pragma unroll
  for (int i = 0; i < 3; ++i) {
    int c = threadIdx.x + i * 256;
    float x = wemb[(long)tk * DMODEL + c] + pemb[(long)(row + 2) * DMODEL + c];
    v[i] = x;
    s += x;
    q += x * x;
  }
#pragma unroll
  for (int off = 32; off; off >>= 1) {
    s += __shfl_down(s, off);
    q += __shfl_down(q, off);
  }
  int w = threadIdx.x >> 6;
  if ((threadIdx.x & 63) == 0) { sm1[w] = s; sm2[w] = q; }
  __syncthreads();
  s = sm1[0] + sm1[1] + sm1[2] + sm1[3];
  q = sm2[0] + sm2[1] + sm2[2] + sm2[3];
  float mu = s * (1.f / DMODEL);
  float var = q * (1.f / DMODEL) - mu * mu;
  float inv = rsqrtf(var + 1e-5f);
#pragma unroll
  for (int i = 0; i < 3; ++i) {
    int c = threadIdx.x + i * 256;
    float y = (v[i] - mu) * inv * gs[c] + gb[c];
    Xb[(long)row * DMODEL + c] = f2b(y);
  }
}

// ---------------------------------------------------------------------------
// Xb = LayerNorm(Xb + P0b + P1b + bias) — bf16 residual, vectorized (G13):
// 192 threads x 4 contiguous bf16 (8B/lane loads). grid=4096.
// ---------------------------------------------------------------------------
__global__ __launch_bounds__(192) void resln2_kernel(
    short* __restrict__ Xb, const short* __restrict__ P0b,
    const short* __restrict__ P1b, const float* __restrict__ bias,
    const float* __restrict__ gs, const float* __restrict__ gb) {
  __shared__ float sm1[3], sm2[3];
  const int row = blockIdx.x;
  const int t = threadIdx.x;
  const int c = t * 4;
  const long ix = (long)row * DMODEL + c;
  s4v xv = *(const s4v*)&Xb[ix];
  s4v p0 = *(const s4v*)&P0b[ix];
  s4v p1 = *(const s4v*)&P1b[ix];
  float4 bb = *(const float4*)&bias[c];
  float v[4];
  v[0] = b2f(xv[0]) + b2f(p0[0]) + b2f(p1[0]) + bb.x;
  v[1] = b2f(xv[1]) + b2f(p0[1]) + b2f(p1[1]) + bb.y;
  v[2] = b2f(xv[2]) + b2f(p0[2]) + b2f(p1[2]) + bb.z;
  v[3] = b2f(xv[3]) + b2f(p0[3]) + b2f(p1[3]) + bb.w;
  float s = v[0] + v[1] + v[2] + v[3];
  float q = v[0] * v[0] + v[1] * v[1] + v[2] * v[2] + v[3] * v[3];
#pragma unroll
  for (int off = 32; off; off >>= 1) {
    s += __shfl_down(s, off);
    q += __shfl_down(q, off);
  }
  const int w = t >> 6;
  if ((t & 63) == 0) { sm1[w] = s; sm2[w] = q; }
  __syncthreads();
  s = sm1[0] + sm1[1] + sm1[2];
  q = sm2[0] + sm2[1] + sm2[2];
  float mu = s * (1.f / DMODEL);
  float var = q * (1.f / DMODEL) - mu * mu;
  float inv = rsqrtf(var + 1e-5f);
  float4 gsv = *(const float4*)&gs[c];
  float4 gbv = *(const float4*)&gb[c];
  s4v y;
  y[0] = f2b((v[0] - mu) * inv * gsv.x + gbv.x);
  y[1] = f2b((v[1] - mu) * inv * gsv.y + gbv.y);
  y[2] = f2b((v[2] - mu) * inv * gsv.z + gbv.z);
  y[3] = f2b((v[3] - mu) * inv * gsv.w + gbv.w);
  *(s4v*)&Xb[ix] = y;
}

// ---------------------------------------------------------------------------
// out[row] = dot(H3[row,:512] (bf16), w4[:,0] (f32)) + b4[0].
// ---------------------------------------------------------------------------
__global__ __launch_bounds__(256) void cls_final_kernel(
    const short* __restrict__ Hh, const float* __restrict__ w4,
    const float* __restrict__ b4, float* __restrict__ out) {
  const int w = threadIdx.x >> 6, lane = threadIdx.x & 63;
  const int row = blockIdx.x * 4 + w;
  float s = 0.f;
#pragma unroll
  for (int j = 0; j < 8; ++j) {
    int k = lane + j * 64;
    s += b2f(Hh[(long)row * 512 + k]) * w4[k * 2];
  }
#pragma unroll
  for (int off = 32; off; off >>= 1) s += __shfl_down(s, off);
  if (lane == 0) out[row] = s + b4[0];
}

// ---------------------------------------------------------------------------
extern "C" void kernel_launch(void* const* d_in, const int* in_sizes, int n_in,
                              void* d_out, int out_size, void* d_ws,
                              size_t ws_size, hipStream_t stream) {
  const int* essay = (const int*)d_in[0];
  const float* wemb = (const float*)d_in[1];
  const float* pemb = (const float*)d_in[2];
  const float* eln_s = (const float*)d_in[3];
  const float* eln_b = (const float*)d_in[4];
  const float* qkv_w = (const float*)d_in[5];
  const float* qkv_b = (const float*)d_in[6];
  const float* aow = (const float*)d_in[7];
  const float* aob = (const float*)d_in[8];
  const float* aln_s = (const float*)d_in[9];
  const float* aln_b = (const float*)d_in[10];
  const float* w1 = (const float*)d_in[11];
  const float* b1 = (const float*)d_in[12];
  const float* w2 = (const float*)d_in[13];
  const float* b2 = (const float*)d_in[14];
  const float* fln_s = (const float*)d_in[15];
  const float* fln_b = (const float*)d_in[16];
  const float* c1w = (const float*)d_in[17];
  const float* c1b = (const float*)d_in[18];
  const float* c2w = (const float*)d_in[19];
  const float* c2b = (const float*)d_in[20];
  const float* c3w = (const float*)d_in[21];
  const float* c3b = (const float*)d_in[22];
  const float* c4w = (const float*)d_in[23];
  const float* c4b = (const float*)d_in[24];

  const long SD = (long)S_LEN * DMODEL;
  const long SF = (long)S_LEN * FFDIM;
  const long SH = (long)S_LEN * 512;
  const long DD = (long)DMODEL * DMODEL;
  const long DF = (long)DMODEL * FFDIM;

  short* P0b = (short*)d_ws;
  short* P1b = P0b + SD;
  short* lwq = P1b + SD;
  short* lwa = lwq + 3 * DD;
  short* lw1 = lwa + DD;
  short* lw2 = lw1 + DF;
  short* c1T = lw2 + DF;
  short* c2T = c1T + (long)DMODEL * 512;
  short* c3T = c2T + 512L * 512;
  short* Xb = c3T + 512L * 512;
  short* QKVb = Xb + SD;   // Q | K row-major; V slice holds V^T [768][4096]
  short* T1b = QKVb + 3 * SD;
  short* T2b = T1b + SD;
  short* H1 = T2b + SF;
  short* H2 = H1 + SH;
  short* H3 = H2 + SH;
  const long needed = (char*)(H3 + SH) - (char*)d_ws;
  if (ws_size < (size_t)needed) return;

  const int* maskp = essay + S_LEN;

  embed_ln_kernel<<<S_LEN, 256, 0, stream>>>(essay, wemb, pemb, eln_s, eln_b,
                                             Xb);

  for (int l = 0; l < NLAYER; ++l) {
    wtr_layer_kernel<<<1728, 256, 0, stream>>>(
        qkv_w + l * 3 * DD, aow + l * DD, w1 + l * DF, w2 + l * DF, lwq, lwa,
        lw1, lw2);

    // QKV: z==0 Q (scaled), z==1 K, z==2 V written transposed in-epilogue
    bgemm_kernel<2, 3><<<dim3(6, 32, 3), 256, 0, stream>>>(
        Xb, lwq, qkv_b + (long)l * 3 * DMODEL, QKVb, DMODEL, DMODEL, DMODEL, DD,
        DMODEL, SD);
    attn_kernel<<<dim3(64, 12), 256, 0, stream>>>(QKVb, QKVb + SD,
                                                  QKVb + 2 * SD, maskp, T1b);
    // attn-out projection: split-K x2 -> bf16 partials P0b,P1b
    bgemm_kernel<0, 2><<<dim3(6, 32, 2), 256, 0, stream>>>(
        T1b, lwa, aob, P0b, DMODEL, DMODEL, 384, 0, 0, SD);
    resln2_kernel<<<S_LEN, 192, 0, stream>>>(Xb, P0b, P1b,
                                             aob + (long)l * DMODEL,
                                             aln_s + (long)l * DMODEL,
                                             aln_b + (long)l * DMODEL);
    // FFN1 (128x128 kernel, GELU epilogue)
    bgemm_kernel<1, 1><<<dim3(24, 32, 1), 256, 0, stream>>>(
        Xb, lw1, b1 + (long)l * FFDIM, T2b, FFDIM, DMODEL, DMODEL, 0, 0, 0);
    // FFN down-projection: split-K x2 -> bf16 partials P0b,P1b
    bgemm_kernel<0, 2><<<dim3(6, 32, 2), 256, 0, stream>>>(
        T2b, lw2, b2, P0b, DMODEL, FFDIM, 1536, 0, 0, SD);
    resln2_kernel<<<S_LEN, 192, 0, stream>>>(Xb, P0b, P1b,
                                             b2 + (long)l * DMODEL,
                                             fln_s + (long)l * DMODEL,
                                             fln_b + (long)l * DMODEL);
  }

  wtr_kernel<<<dim3(8, 12), 256, 0, stream>>>(c1w, c1T, DMODEL, 512);
  wtr_kernel<<<dim3(8, 8), 256, 0, stream>>>(c2w, c2T, 512, 512);
  wtr_kernel<<<dim3(8, 8), 256, 0, stream>>>(c3w, c3T, 512, 512);

  bgemm_kernel<0, 1><<<dim3(4, 32, 1), 256, 0, stream>>>(
      Xb, c1T, c1b, H1, 512, DMODEL, DMODEL, 0, 0, 0);
  bgemm_kernel<0, 1><<<dim3(4, 32, 1), 256, 0, stream>>>(H1, c2T, c2b, H2, 512,
                                                         512, 512, 0, 0, 0);
  bgemm_kernel<0, 1><<<dim3(4, 32, 1), 256, 0, stream>>>(H2, c3T, c3b, H3, 512,
                                                         512, 512, 0, 0, 0);
  cls_final_kernel<<<S_LEN / 4, 256, 0, stream>>>(H3, c4w, c4b, (float*)d_out);
}